// Round 1
// baseline (1923.271 us; speedup 1.0000x reference)
//
#include <hip/hip_runtime.h>
#include <math.h>
#include <float.h>

// VideoQuantizer: rmsnorm -> per-subvector nearest codeword (argmin over K) -> gather -> rmsnorm
// B=8 T=1024 D=1024 Q=8 K=4096 d=128
#define B_   8
#define T_   1024
#define D_   1024
#define Q_   8
#define K_   4096
#define dd_  128
#define ROWS (B_ * T_)   // 8192

#define TM 64
#define TN 64

// ---------------- c2[q][k] = sum_d cb[q][k][d]^2 : one wave per codeword ----------------
__global__ void k_c2(const float* __restrict__ cb, float* __restrict__ c2) {
    int gw   = (blockIdx.x * blockDim.x + threadIdx.x) >> 6;  // 0..32767
    int lane = threadIdx.x & 63;
    const float2 v = *(const float2*)(cb + (size_t)gw * dd_ + lane * 2);
    float ss = v.x * v.x + v.y * v.y;
    #pragma unroll
    for (int o = 32; o > 0; o >>= 1) ss += __shfl_xor(ss, o, 64);
    if (lane == 0) c2[gw] = ss;
}

// ---------------- input rmsnorm: one block (256 thr) per row ----------------
__global__ void k_rms_in(const float* __restrict__ x, const float* __restrict__ w,
                         float* __restrict__ xn) {
    int row = blockIdx.x;
    int t   = threadIdx.x;
    const float4 v = *(const float4*)(x + (size_t)row * D_ + t * 4);
    float ss = v.x * v.x + v.y * v.y + v.z * v.z + v.w * v.w;
    #pragma unroll
    for (int o = 32; o > 0; o >>= 1) ss += __shfl_xor(ss, o, 64);
    __shared__ float acc[4];
    if ((t & 63) == 0) acc[t >> 6] = ss;
    __syncthreads();
    float tot = (acc[0] + acc[1]) + (acc[2] + acc[3]);
    float sc  = 1.0f / sqrtf(tot * (1.0f / D_) + 1e-5f);
    const float4 wv = *(const float4*)(w + t * 4);
    float4 o;
    o.x = v.x * sc * wv.x;
    o.y = v.y * sc * wv.y;
    o.z = v.z * sc * wv.z;
    o.w = v.w * sc * wv.w;
    *(float4*)(xn + (size_t)row * D_ + t * 4) = o;
}

// ---------------- fused distance GEMM + argmin ----------------
// grid (ROWS/TM, Q_), block 256. score[r][k] = c2[k] - 2 * dot(xn_q[r], cb_q[k])
// Tiles stored d-major in LDS so fragment reads are contiguous ds_read_b128.
__global__ void k_dist(const float* __restrict__ xn, const float* __restrict__ cb,
                       const float* __restrict__ c2, int* __restrict__ idx_i,
                       float* __restrict__ idx_f) {
    __shared__ float xs[dd_][TM];   // 32 KB, d-major
    __shared__ float cs[dd_][TN];   // 32 KB, d-major
    const int t    = threadIdx.x;           // 0..255
    const int tx   = t & 15, ty = t >> 4;   // 16 x 16
    const int rt   = blockIdx.x, q = blockIdx.y;
    const int row0 = rt * TM;
    const float* cbq = cb + (size_t)q * K_ * dd_;
    const float* c2q = c2 + q * K_;

    // stage x tile: rows row0..row0+63, cols q*128..+128, transposed to d-major
    #pragma unroll
    for (int i = 0; i < 8; i++) {
        int f = i * 256 + t;            // float4 index: 64 rows x 32 f4
        int r = f >> 5, c4 = f & 31;
        float4 v = *(const float4*)(xn + (size_t)(row0 + r) * D_ + q * dd_ + c4 * 4);
        xs[c4 * 4 + 0][r] = v.x;
        xs[c4 * 4 + 1][r] = v.y;
        xs[c4 * 4 + 2][r] = v.z;
        xs[c4 * 4 + 3][r] = v.w;
    }

    float best_s[4];
    int   best_k[4];
    #pragma unroll
    for (int ii = 0; ii < 4; ii++) { best_s[ii] = FLT_MAX; best_k[ii] = 0; }

    for (int kt = 0; kt < K_ / TN; kt++) {
        const int k0 = kt * TN;
        __syncthreads();                 // previous compute done (also covers xs on kt=0)
        #pragma unroll
        for (int i = 0; i < 8; i++) {
            int f = i * 256 + t;
            int r = f >> 5, c4 = f & 31;
            float4 v = *(const float4*)(cbq + (size_t)(k0 + r) * dd_ + c4 * 4);
            cs[c4 * 4 + 0][r] = v.x;
            cs[c4 * 4 + 1][r] = v.y;
            cs[c4 * 4 + 2][r] = v.z;
            cs[c4 * 4 + 3][r] = v.w;
        }
        __syncthreads();

        float acc[4][4];
        #pragma unroll
        for (int ii = 0; ii < 4; ii++)
            #pragma unroll
            for (int jj = 0; jj < 4; jj++) acc[ii][jj] = 0.0f;

        #pragma unroll 8
        for (int dd = 0; dd < dd_; dd++) {
            const float4 a = *(const float4*)&xs[dd][ty * 4];
            const float4 b = *(const float4*)&cs[dd][tx * 4];
            acc[0][0] += a.x * b.x; acc[0][1] += a.x * b.y; acc[0][2] += a.x * b.z; acc[0][3] += a.x * b.w;
            acc[1][0] += a.y * b.x; acc[1][1] += a.y * b.y; acc[1][2] += a.y * b.z; acc[1][3] += a.y * b.w;
            acc[2][0] += a.z * b.x; acc[2][1] += a.z * b.y; acc[2][2] += a.z * b.z; acc[2][3] += a.z * b.w;
            acc[3][0] += a.w * b.x; acc[3][1] += a.w * b.y; acc[3][2] += a.w * b.z; acc[3][3] += a.w * b.w;
        }

        #pragma unroll
        for (int jj = 0; jj < 4; jj++) {
            const int   k  = k0 + tx * 4 + jj;
            const float cc = c2q[k];
            #pragma unroll
            for (int ii = 0; ii < 4; ii++) {
                float s = cc - 2.0f * acc[ii][jj];
                // first-min semantics: strict <, tie -> smaller k
                if (s < best_s[ii] || (s == best_s[ii] && k < best_k[ii])) {
                    best_s[ii] = s;
                    best_k[ii] = k;
                }
            }
        }
    }

    // cross-thread argmin reduction per row (reuse tile LDS as scratch)
    __syncthreads();
    float* rbs = &xs[0][0];   // [64][16]
    int*   rbk = (int*)&cs[0][0];
    #pragma unroll
    for (int ii = 0; ii < 4; ii++) {
        rbs[(ty * 4 + ii) * 16 + tx] = best_s[ii];
        rbk[(ty * 4 + ii) * 16 + tx] = best_k[ii];
    }
    __syncthreads();
    if (t < TM) {
        float bs = FLT_MAX;
        int   bk = 0x7fffffff;
        #pragma unroll
        for (int x = 0; x < 16; x++) {
            float s = rbs[t * 16 + x];
            int   k = rbk[t * 16 + x];
            if (s < bs || (s == bs && k < bk)) { bs = s; bk = k; }
        }
        int gr = row0 + t;
        idx_i[gr * Q_ + q] = bk;
        idx_f[gr * Q_ + q] = (float)bk;   // harness reads whole d_out as fp32
    }
}

// ---------------- gather selected codewords + output rmsnorm ----------------
__global__ void k_out(const float* __restrict__ cb, const int* __restrict__ idx_i,
                      const float* __restrict__ w, float* __restrict__ out) {
    int row = blockIdx.x;
    int t   = threadIdx.x;
    __shared__ int   sidx[Q_];
    __shared__ float acc[4];
    if (t < Q_) sidx[t] = idx_i[row * Q_ + t];
    __syncthreads();
    int col = t * 4;
    int q   = col >> 7;
    int dc  = col & 127;
    const float4 v = *(const float4*)(cb + ((size_t)q * K_ + sidx[q]) * dd_ + dc);
    float ss = v.x * v.x + v.y * v.y + v.z * v.z + v.w * v.w;
    #pragma unroll
    for (int o = 32; o > 0; o >>= 1) ss += __shfl_xor(ss, o, 64);
    if ((t & 63) == 0) acc[t >> 6] = ss;
    __syncthreads();
    float tot = (acc[0] + acc[1]) + (acc[2] + acc[3]);
    float sc  = 1.0f / sqrtf(tot * (1.0f / D_) + 1e-5f);
    const float4 wv = *(const float4*)(w + col);
    float4 o;
    o.x = v.x * sc * wv.x;
    o.y = v.y * sc * wv.y;
    o.z = v.z * sc * wv.z;
    o.w = v.w * sc * wv.w;
    *(float4*)(out + (size_t)row * D_ + col) = o;
}

extern "C" void kernel_launch(void* const* d_in, const int* in_sizes, int n_in,
                              void* d_out, int out_size, void* d_ws, size_t ws_size,
                              hipStream_t stream) {
    const float* x     = (const float*)d_in[0];   // [8,1024,1024]
    const float* cb    = (const float*)d_in[1];   // [8,4096,128]
    const float* w_in  = (const float*)d_in[2];   // [1024]
    const float* w_out = (const float*)d_in[3];   // [1024]

    float* out  = (float*)d_out;                  // [8192*1024] fp32
    float* idxf = out + (size_t)ROWS * D_;        // [8192*8] idx as float
    float* c2   = (float*)d_ws;                   // 32768 floats
    int*   idxi = (int*)d_ws + Q_ * K_;           // 65536 ints

    // 1) codeword squared norms
    k_c2<<<dim3((Q_ * K_) / 4), 256, 0, stream>>>(cb, c2);
    // 2) input rmsnorm -> store xn into the `out` region (phase 4 overwrites it)
    k_rms_in<<<dim3(ROWS), 256, 0, stream>>>(x, w_in, out);
    // 3) fused distance GEMM + argmin
    k_dist<<<dim3(ROWS / TM, Q_), 256, 0, stream>>>(out, cb, c2, idxi, idxf);
    // 4) gather + output rmsnorm
    k_out<<<dim3(ROWS), 256, 0, stream>>>(cb, idxi, w_out, out);
}

// Round 2
// 365.949 us; speedup vs baseline: 5.2556x; 5.2556x over previous
//
#include <hip/hip_runtime.h>
#include <math.h>
#include <float.h>

// VideoQuantizer: rmsnorm -> per-subvector argmin over 4096 codewords -> gather -> rmsnorm
// B=8 T=1024 D=1024 Q=8 K=4096 d=128
#define B_     8
#define T_     1024
#define D_     1024
#define Q_     8
#define K_     4096
#define dd_    128
#define ROWS   8192
#define CHUNKN 64              // codewords per chunk
#define NCHUNK (K_ / CHUNKN)   // 64
#define TAU    0.01f           // rescue threshold (>> 3-pass bf16 worst-case error ~1e-3)

typedef __attribute__((ext_vector_type(8))) short bf16x8;
typedef __attribute__((ext_vector_type(4))) float f32x4;
typedef __attribute__((ext_vector_type(4))) unsigned int u32x4;

typedef const __attribute__((address_space(1))) unsigned int* gas_p;
typedef __attribute__((address_space(3))) unsigned int* las_p;

__device__ inline unsigned short f2bf_rtn(float x) {
    union { float f; unsigned u; } v; v.f = x;
    unsigned r = v.u + 0x7fffu + ((v.u >> 16) & 1u);
    return (unsigned short)(r >> 16);
}
__device__ inline float bf2f(unsigned short h) {
    union { unsigned u; float f; } v; v.u = ((unsigned)h) << 16; return v.f;
}

// ---------------- c2[q][k] = ||cb[q][k]||^2 : one wave per codeword ----------------
__global__ void k_c2(const float* __restrict__ cb, float* __restrict__ c2) {
    int gw   = (blockIdx.x * blockDim.x + threadIdx.x) >> 6;
    int lane = threadIdx.x & 63;
    const float2 v = *(const float2*)(cb + (size_t)gw * dd_ + lane * 2);
    float ss = v.x * v.x + v.y * v.y;
    #pragma unroll
    for (int o = 32; o > 0; o >>= 1) ss += __shfl_xor(ss, o, 64);
    if (lane == 0) c2[gw] = ss;
}

// ---------------- input rmsnorm: one block per row ----------------
__global__ void k_rms_in(const float* __restrict__ x, const float* __restrict__ w,
                         float* __restrict__ xn) {
    int row = blockIdx.x;
    int t   = threadIdx.x;
    const float4 v = *(const float4*)(x + (size_t)row * D_ + t * 4);
    float ss = v.x * v.x + v.y * v.y + v.z * v.z + v.w * v.w;
    #pragma unroll
    for (int o = 32; o > 0; o >>= 1) ss += __shfl_xor(ss, o, 64);
    __shared__ float acc[4];
    if ((t & 63) == 0) acc[t >> 6] = ss;
    __syncthreads();
    float tot = (acc[0] + acc[1]) + (acc[2] + acc[3]);
    float sc  = 1.0f / sqrtf(tot * (1.0f / D_) + 1e-5f);
    const float4 wv = *(const float4*)(w + t * 4);
    float4 o;
    o.x = v.x * sc * wv.x; o.y = v.y * sc * wv.y;
    o.z = v.z * sc * wv.z; o.w = v.w * sc * wv.w;
    *(float4*)(xn + (size_t)row * D_ + t * 4) = o;
}

// ---------------- build swizzled bf16 hi/lo codebook panels ----------------
// panels[q][c][plane][n 0..63][slot 0..15][8 bf16]; slot = j ^ (n&15)
// so the linear LDS image from global_load_lds gives conflict-light frag reads.
__global__ void k_prep_b(const float* __restrict__ cb, unsigned short* __restrict__ panels) {
    int c = blockIdx.x, q = blockIdx.y, t = threadIdx.x;
    const float* src = cb + ((size_t)q * K_ + c * CHUNKN) * dd_;
    unsigned short* dst = panels + (size_t)(q * NCHUNK + c) * 16384;  // 32KB per (q,c)
    #pragma unroll
    for (int i = 0; i < 4; i++) {
        int sid = i * 256 + t;          // 1024 (n,j) slots
        int n = sid >> 4, j = sid & 15;
        const float* sp = src + n * dd_ + j * 8;
        unsigned short h[8], l[8];
        #pragma unroll
        for (int e = 0; e < 8; e++) {
            float x = sp[e];
            h[e] = f2bf_rtn(x);
            l[e] = f2bf_rtn(x - bf2f(h[e]));
        }
        int slot = j ^ (n & 15);
        u32x4 H, L;
        H.x = (unsigned)h[0] | ((unsigned)h[1] << 16);
        H.y = (unsigned)h[2] | ((unsigned)h[3] << 16);
        H.z = (unsigned)h[4] | ((unsigned)h[5] << 16);
        H.w = (unsigned)h[6] | ((unsigned)h[7] << 16);
        L.x = (unsigned)l[0] | ((unsigned)l[1] << 16);
        L.y = (unsigned)l[2] | ((unsigned)l[3] << 16);
        L.z = (unsigned)l[4] | ((unsigned)l[5] << 16);
        L.w = (unsigned)l[6] | ((unsigned)l[7] << 16);
        *(u32x4*)&dst[(n * 16 + slot) * 8]        = H;   // hi plane @ 0
        *(u32x4*)&dst[8192 + (n * 16 + slot) * 8] = L;   // lo plane @ 16KB
    }
}

// ---------------- fused 3-pass split-bf16 MFMA distance + top-2 argmin ----------------
// grid (ROWS/128, Q_), 256 threads = 4 waves (2x2 over 128M x 64N per chunk)
__launch_bounds__(256, 2)
__global__ void k_dist(const float* __restrict__ xn, const unsigned short* __restrict__ panels,
                       const float* __restrict__ c2, int* __restrict__ idxi,
                       float* __restrict__ idxf, int* __restrict__ list,
                       int* __restrict__ counter) {
    __shared__ char smem[50688];   // staging 32KB; reduce 3*128*33*4 = 50688

    const int t    = threadIdx.x;
    const int lane = t & 63, wave = t >> 6;
    const int wm = wave >> 1, wn = wave & 1;
    const int col = lane & 15, quad = lane >> 4;
    const int q = blockIdx.y;
    const int row0 = blockIdx.x * 128;

    // A fragments (register-resident): 4 m-tiles x 4 k-steps, hi & lo bf16
    bf16x8 ah[4][4], al[4][4];
    #pragma unroll
    for (int mt = 0; mt < 4; mt++) {
        #pragma unroll
        for (int kt = 0; kt < 4; kt++) {
            const float* ap = xn + (size_t)(row0 + wm * 64 + mt * 16 + col) * D_
                              + q * dd_ + kt * 32 + quad * 8;
            f32x4 v0 = *(const f32x4*)ap;
            f32x4 v1 = *(const f32x4*)(ap + 4);
            #pragma unroll
            for (int e = 0; e < 8; e++) {
                float x = (e < 4) ? v0[e] : v1[e - 4];
                unsigned short hh = f2bf_rtn(x);
                ah[mt][kt][e] = (short)hh;
                al[mt][kt][e] = (short)f2bf_rtn(x - bf2f(hh));
            }
        }
    }

    float s1[16], s2[16];
    int   k1[16];
    #pragma unroll
    for (int i = 0; i < 16; i++) { s1[i] = FLT_MAX; s2[i] = FLT_MAX; k1[i] = 0; }

    const size_t panq = (size_t)q * NCHUNK * 16384;
    const float* c2q  = c2 + q * K_;

    for (int c = 0; c < NCHUNK; c++) {
        __syncthreads();
        const unsigned short* src = panels + panq + (size_t)c * 16384;
        #pragma unroll
        for (int i = 0; i < 8; i++) {
            int boff = i * 4096 + t * 16;
            __builtin_amdgcn_global_load_lds((gas_p)((const char*)src + boff),
                                             (las_p)(smem + boff), 16, 0, 0);
        }
        __syncthreads();

        f32x4 acc[4][2];
        #pragma unroll
        for (int mt = 0; mt < 4; mt++) { acc[mt][0] = 0.0f; acc[mt][1] = 0.0f; }

        #pragma unroll
        for (int kt = 0; kt < 4; kt++) {
            const int sw = ((quad + kt * 4) ^ col) * 16;
            const int a0 = (wn * 32 + col) * 256 + sw;
            const int a1 = (wn * 32 + 16 + col) * 256 + sw;
            bf16x8 bh0 = *(const bf16x8*)(smem + a0);
            bf16x8 bh1 = *(const bf16x8*)(smem + a1);
            bf16x8 bl0 = *(const bf16x8*)(smem + 16384 + a0);
            bf16x8 bl1 = *(const bf16x8*)(smem + 16384 + a1);
            #pragma unroll
            for (int mt = 0; mt < 4; mt++) {
                acc[mt][0] = __builtin_amdgcn_mfma_f32_16x16x32_bf16(ah[mt][kt], bh0, acc[mt][0], 0, 0, 0);
                acc[mt][1] = __builtin_amdgcn_mfma_f32_16x16x32_bf16(ah[mt][kt], bh1, acc[mt][1], 0, 0, 0);
                acc[mt][0] = __builtin_amdgcn_mfma_f32_16x16x32_bf16(al[mt][kt], bh0, acc[mt][0], 0, 0, 0);
                acc[mt][1] = __builtin_amdgcn_mfma_f32_16x16x32_bf16(al[mt][kt], bh1, acc[mt][1], 0, 0, 0);
                acc[mt][0] = __builtin_amdgcn_mfma_f32_16x16x32_bf16(ah[mt][kt], bl0, acc[mt][0], 0, 0, 0);
                acc[mt][1] = __builtin_amdgcn_mfma_f32_16x16x32_bf16(ah[mt][kt], bl1, acc[mt][1], 0, 0, 0);
            }
        }

        const int   kb  = c * 64 + wn * 32 + col;
        const float c20 = c2q[kb];
        const float c21 = c2q[kb + 16];
        #pragma unroll
        for (int mt = 0; mt < 4; mt++) {
            #pragma unroll
            for (int r = 0; r < 4; r++) {
                const int sl = mt * 4 + r;
                {
                    float s = fmaf(-2.0f, acc[mt][0][r], c20);
                    bool  b = s < s1[sl];
                    s2[sl] = fminf(s2[sl], fmaxf(s1[sl], s));
                    s1[sl] = fminf(s1[sl], s);
                    k1[sl] = b ? kb : k1[sl];
                }
                {
                    float s = fmaf(-2.0f, acc[mt][1][r], c21);
                    bool  b = s < s1[sl];
                    s2[sl] = fminf(s2[sl], fmaxf(s1[sl], s));
                    s1[sl] = fminf(s1[sl], s);
                    k1[sl] = b ? (kb + 16) : k1[sl];
                }
            }
        }
    }

    // cross-lane top-2 merge per row via LDS (stride 33 to avoid bank conflicts)
    __syncthreads();
    float* rs1 = (float*)smem;                 // [128][33]
    int*   rk1 = (int*)(smem + 16896);
    float* rs2 = (float*)(smem + 33792);
    #pragma unroll
    for (int mt = 0; mt < 4; mt++) {
        #pragma unroll
        for (int r = 0; r < 4; r++) {
            int sl = mt * 4 + r;
            int row_l = wm * 64 + mt * 16 + quad * 4 + r;
            int e = wn * 16 + col;
            rs1[row_l * 33 + e] = s1[sl];
            rk1[row_l * 33 + e] = k1[sl];
            rs2[row_l * 33 + e] = s2[sl];
        }
    }
    __syncthreads();
    if (t < 128) {
        float bs = FLT_MAX, bs2 = FLT_MAX;
        int   bk = 0x7fffffff;
        for (int e = 0; e < 32; e++) {
            float s   = rs1[t * 33 + e];
            int   k   = rk1[t * 33 + e];
            float s2e = rs2[t * 33 + e];
            bs2 = fminf(fminf(bs2, s2e), fmaxf(bs, s));
            if (s < bs || (s == bs && k < bk)) { bs = s; bk = k; }
        }
        int rg = row0 + t;
        idxi[rg * Q_ + q] = bk;
        idxf[rg * Q_ + q] = (float)bk;
        if (bs2 - bs < TAU) {
            int p = atomicAdd(counter, 1);
            list[p] = rg * Q_ + q;
        }
    }
}

// ---------------- exact fp32 re-score of flagged (row,q) pairs ----------------
__global__ void k_rescue(const float* __restrict__ xn, const float* __restrict__ cb,
                         const float* __restrict__ c2, const int* __restrict__ list,
                         const int* __restrict__ counter, int* __restrict__ idxi,
                         float* __restrict__ idxf) {
    __shared__ float xq[128];
    __shared__ float bs_sh[256];
    __shared__ int   bk_sh[256];
    const int n = *counter;
    const int t = threadIdx.x;
    for (int it = blockIdx.x; it < n; it += gridDim.x) {
        __syncthreads();
        int item = list[it];
        int rg = item >> 3, q = item & 7;
        if (t < 128) xq[t] = xn[(size_t)rg * D_ + q * dd_ + t];
        __syncthreads();
        float bs = FLT_MAX; int bk = 0x7fffffff;
        for (int i = 0; i < 16; i++) {
            int k = i * 256 + t;
            const float* cp = cb + ((size_t)q * K_ + k) * dd_;
            float dot = 0.0f;
            #pragma unroll 8
            for (int d = 0; d < dd_; d += 4) {
                f32x4 cv = *(const f32x4*)(cp + d);
                dot = fmaf(cv.x, xq[d],     dot);
                dot = fmaf(cv.y, xq[d + 1], dot);
                dot = fmaf(cv.z, xq[d + 2], dot);
                dot = fmaf(cv.w, xq[d + 3], dot);
            }
            float s = c2[q * K_ + k] - 2.0f * dot;
            if (s < bs || (s == bs && k < bk)) { bs = s; bk = k; }
        }
        bs_sh[t] = bs; bk_sh[t] = bk;
        __syncthreads();
        if (t == 0) {
            float B = FLT_MAX; int K2 = 0x7fffffff;
            for (int e = 0; e < 256; e++) {
                if (bs_sh[e] < B || (bs_sh[e] == B && bk_sh[e] < K2)) { B = bs_sh[e]; K2 = bk_sh[e]; }
            }
            idxi[item] = K2;
            idxf[item] = (float)K2;
        }
    }
}

// ---------------- gather + output rmsnorm ----------------
__global__ void k_out(const float* __restrict__ cb, const int* __restrict__ idx_i,
                      const float* __restrict__ w, float* __restrict__ out) {
    int row = blockIdx.x;
    int t   = threadIdx.x;
    __shared__ int   sidx[Q_];
    __shared__ float acc[4];
    if (t < Q_) sidx[t] = idx_i[row * Q_ + t];
    __syncthreads();
    int col = t * 4;
    int q   = col >> 7;
    int dc  = col & 127;
    const float4 v = *(const float4*)(cb + ((size_t)q * K_ + sidx[q]) * dd_ + dc);
    float ss = v.x * v.x + v.y * v.y + v.z * v.z + v.w * v.w;
    #pragma unroll
    for (int o = 32; o > 0; o >>= 1) ss += __shfl_xor(ss, o, 64);
    if ((t & 63) == 0) acc[t >> 6] = ss;
    __syncthreads();
    float tot = (acc[0] + acc[1]) + (acc[2] + acc[3]);
    float sc  = 1.0f / sqrtf(tot * (1.0f / D_) + 1e-5f);
    const float4 wv = *(const float4*)(w + col);
    float4 o;
    o.x = v.x * sc * wv.x; o.y = v.y * sc * wv.y;
    o.z = v.z * sc * wv.z; o.w = v.w * sc * wv.w;
    *(float4*)(out + (size_t)row * D_ + col) = o;
}

extern "C" void kernel_launch(void* const* d_in, const int* in_sizes, int n_in,
                              void* d_out, int out_size, void* d_ws, size_t ws_size,
                              hipStream_t stream) {
    const float* x     = (const float*)d_in[0];
    const float* cb    = (const float*)d_in[1];
    const float* w_in  = (const float*)d_in[2];
    const float* w_out = (const float*)d_in[3];

    float* out  = (float*)d_out;
    float* idxf = out + (size_t)ROWS * D_;

    // ws: panels 16MB | c2 128KB | list 256KB | counter | idxi 256KB  (~16.7MB)
    unsigned short* panels = (unsigned short*)d_ws;
    float* c2      = (float*)((char*)d_ws + (16u << 20));
    int*   list    = (int*)((char*)d_ws + (16u << 20) + (128u << 10));
    int*   counter = list + 65536;
    int*   idxi    = counter + 64;

    hipMemsetAsync(counter, 0, sizeof(int), stream);
    k_c2    <<<dim3((Q_ * K_) / 4), 256, 0, stream>>>(cb, c2);
    k_prep_b<<<dim3(NCHUNK, Q_),    256, 0, stream>>>(cb, panels);
    k_rms_in<<<dim3(ROWS),          256, 0, stream>>>(x, w_in, out);
    k_dist  <<<dim3(ROWS / 128, Q_), 256, 0, stream>>>(out, panels, c2, idxi, idxf, list, counter);
    k_rescue<<<dim3(256),           256, 0, stream>>>(out, cb, c2, list, counter, idxi, idxf);
    k_out   <<<dim3(ROWS),          256, 0, stream>>>(cb, idxi, w_out, out);
}

// Round 3
// 351.961 us; speedup vs baseline: 5.4644x; 1.0397x over previous
//
#include <hip/hip_runtime.h>
#include <math.h>
#include <float.h>

// VideoQuantizer: rmsnorm -> per-subvector argmin over 4096 codewords -> gather -> rmsnorm
// B=8 T=1024 D=1024 Q=8 K=4096 d=128
#define B_     8
#define T_     1024
#define D_     1024
#define Q_     8
#define K_     4096
#define dd_    128
#define ROWS   8192
#define CHUNKN 64              // codewords per chunk
#define NCHUNK (K_ / CHUNKN)   // 64
#define TAU    0.02f           // rescue threshold (>> trunc-split 3-pass error ~4e-3 worst)

typedef __attribute__((ext_vector_type(8))) short bf16x8;
typedef __attribute__((ext_vector_type(4))) float f32x4;
typedef __attribute__((ext_vector_type(4))) unsigned int u32x4;

typedef const __attribute__((address_space(1))) unsigned int* gas_p;
typedef __attribute__((address_space(3))) unsigned int* las_p;

__device__ inline float bf2f(unsigned short h) {
    union { unsigned u; float f; } v; v.u = ((unsigned)h) << 16; return v.f;
}
__device__ inline unsigned f2u(float x) { union { float f; unsigned u; } v; v.f = x; return v.u; }

// ---------------- input rmsnorm: one block per row ----------------
__global__ void k_rms_in(const float* __restrict__ x, const float* __restrict__ w,
                         float* __restrict__ xn) {
    int row = blockIdx.x;
    int t   = threadIdx.x;
    const float4 v = *(const float4*)(x + (size_t)row * D_ + t * 4);
    float ss = v.x * v.x + v.y * v.y + v.z * v.z + v.w * v.w;
    #pragma unroll
    for (int o = 32; o > 0; o >>= 1) ss += __shfl_xor(ss, o, 64);
    __shared__ float acc[4];
    if ((t & 63) == 0) acc[t >> 6] = ss;
    __syncthreads();
    float tot = (acc[0] + acc[1]) + (acc[2] + acc[3]);
    float sc  = 1.0f / sqrtf(tot * (1.0f / D_) + 1e-5f);
    const float4 wv = *(const float4*)(w + t * 4);
    float4 o;
    o.x = v.x * sc * wv.x; o.y = v.y * sc * wv.y;
    o.z = v.z * sc * wv.z; o.w = v.w * sc * wv.w;
    *(float4*)(xn + (size_t)row * D_ + t * 4) = o;
}

// ---------------- fused: build swizzled bf16 hi/lo panels + c2 + zero counter ----------------
// panels[q][c][plane][n 0..63][slot 0..15][8 bf16]; slot = j ^ (n&15)
// trunc split: hi = top16(x), lo = top16(x - bf(hi))  (~5 VALU/elem vs ~11 for RTN)
__global__ void k_prep(const float* __restrict__ cb, unsigned short* __restrict__ panels,
                       float* __restrict__ c2, int* __restrict__ counter) {
    int c = blockIdx.x, q = blockIdx.y, t = threadIdx.x;
    if (c == 0 && q == 0 && t == 0) *counter = 0;
    const float* src = cb + ((size_t)q * K_ + c * CHUNKN) * dd_;
    unsigned short* dst = panels + (size_t)(q * NCHUNK + c) * 16384;  // 32KB per (q,c)
    #pragma unroll
    for (int i = 0; i < 4; i++) {
        int sid = i * 256 + t;          // 1024 (n,j) slots
        int n = sid >> 4, j = sid & 15;
        const float* sp = src + n * dd_ + j * 8;
        f32x4 v0 = *(const f32x4*)sp;
        f32x4 v1 = *(const f32x4*)(sp + 4);
        float xs[8] = {v0.x, v0.y, v0.z, v0.w, v1.x, v1.y, v1.z, v1.w};
        unsigned hu[8], lu[8];
        float ss = 0.0f;
        #pragma unroll
        for (int e = 0; e < 8; e++) {
            float x = xs[e];
            ss = fmaf(x, x, ss);
            unsigned u = f2u(x);
            hu[e] = u;                                    // keep full; use top 16
            float r = x - bf2f((unsigned short)(u >> 16));
            lu[e] = f2u(r);
        }
        int slot = j ^ (n & 15);
        u32x4 H, L;
        H.x = (hu[0] >> 16) | (hu[1] & 0xFFFF0000u);
        H.y = (hu[2] >> 16) | (hu[3] & 0xFFFF0000u);
        H.z = (hu[4] >> 16) | (hu[5] & 0xFFFF0000u);
        H.w = (hu[6] >> 16) | (hu[7] & 0xFFFF0000u);
        L.x = (lu[0] >> 16) | (lu[1] & 0xFFFF0000u);
        L.y = (lu[2] >> 16) | (lu[3] & 0xFFFF0000u);
        L.z = (lu[4] >> 16) | (lu[5] & 0xFFFF0000u);
        L.w = (lu[6] >> 16) | (lu[7] & 0xFFFF0000u);
        *(u32x4*)&dst[(n * 16 + slot) * 8]        = H;   // hi plane @ 0
        *(u32x4*)&dst[8192 + (n * 16 + slot) * 8] = L;   // lo plane @ 16KB
        // c2: reduce ss over the 16 lanes sharing n (contiguous 16-lane group in-wave)
        ss += __shfl_xor(ss, 1, 64);
        ss += __shfl_xor(ss, 2, 64);
        ss += __shfl_xor(ss, 4, 64);
        ss += __shfl_xor(ss, 8, 64);
        if (j == 0) c2[q * K_ + c * CHUNKN + n] = ss;
    }
}

// ---------------- fused 3-pass split-bf16 MFMA distance + top-2 argmin ----------------
// grid (ROWS/128, Q_), 256 threads = 4 waves (2x2 over 128M x 64N per chunk)
// Double-buffered staging: prefetch chunk c+1 while computing c.
__launch_bounds__(256, 2)
__global__ void k_dist(const float* __restrict__ xn, const unsigned short* __restrict__ panels,
                       const float* __restrict__ c2, int* __restrict__ idxi,
                       float* __restrict__ idxf, int* __restrict__ list,
                       int* __restrict__ counter) {
    __shared__ char smem[65536];   // 2 x 32KB staging; reduce scratch (50688B) overlaid after loop

    const int t    = threadIdx.x;
    const int lane = t & 63, wave = t >> 6;
    const int wm = wave >> 1, wn = wave & 1;
    const int col = lane & 15, quad = lane >> 4;
    const int q = blockIdx.y;
    const int row0 = blockIdx.x * 128;

    // A fragments (register-resident): 4 m-tiles x 4 k-steps, hi & lo bf16 (trunc split)
    bf16x8 ah[4][4], al[4][4];
    #pragma unroll
    for (int mt = 0; mt < 4; mt++) {
        #pragma unroll
        for (int kt = 0; kt < 4; kt++) {
            const float* ap = xn + (size_t)(row0 + wm * 64 + mt * 16 + col) * D_
                              + q * dd_ + kt * 32 + quad * 8;
            f32x4 v0 = *(const f32x4*)ap;
            f32x4 v1 = *(const f32x4*)(ap + 4);
            #pragma unroll
            for (int e = 0; e < 8; e++) {
                float x = (e < 4) ? v0[e] : v1[e - 4];
                unsigned short hh = (unsigned short)(f2u(x) >> 16);
                float r = x - bf2f(hh);
                ah[mt][kt][e] = (short)hh;
                al[mt][kt][e] = (short)(unsigned short)(f2u(r) >> 16);
            }
        }
    }

    float s1[16], s2[16];
    int   k1[16];
    #pragma unroll
    for (int i = 0; i < 16; i++) { s1[i] = FLT_MAX; s2[i] = FLT_MAX; k1[i] = 0; }

    const size_t panq = (size_t)q * NCHUNK * 16384;
    const float* c2q  = c2 + q * K_;

    // preload chunk 0 into buffer 0
    {
        const unsigned short* src = panels + panq;
        #pragma unroll
        for (int i = 0; i < 8; i++) {
            int boff = i * 4096 + t * 16;
            __builtin_amdgcn_global_load_lds((gas_p)((const char*)src + boff),
                                             (las_p)(smem + boff), 16, 0, 0);
        }
    }

    for (int c = 0; c < NCHUNK; c++) {
        __syncthreads();   // drains prefetch of chunk c + prior reads of the other buffer
        if (c + 1 < NCHUNK) {
            const unsigned short* src = panels + panq + (size_t)(c + 1) * 16384;
            char* stage = smem + ((c + 1) & 1) * 32768;
            #pragma unroll
            for (int i = 0; i < 8; i++) {
                int boff = i * 4096 + t * 16;
                __builtin_amdgcn_global_load_lds((gas_p)((const char*)src + boff),
                                                 (las_p)(stage + boff), 16, 0, 0);
            }
        }
        const char* cbuf = smem + (c & 1) * 32768;

        f32x4 acc[4][2];
        #pragma unroll
        for (int mt = 0; mt < 4; mt++) { acc[mt][0] = 0.0f; acc[mt][1] = 0.0f; }

        #pragma unroll
        for (int kt = 0; kt < 4; kt++) {
            const int sw = ((quad + kt * 4) ^ col) * 16;
            const int a0 = (wn * 32 + col) * 256 + sw;
            const int a1 = (wn * 32 + 16 + col) * 256 + sw;
            bf16x8 bh0 = *(const bf16x8*)(cbuf + a0);
            bf16x8 bh1 = *(const bf16x8*)(cbuf + a1);
            bf16x8 bl0 = *(const bf16x8*)(cbuf + 16384 + a0);
            bf16x8 bl1 = *(const bf16x8*)(cbuf + 16384 + a1);
            #pragma unroll
            for (int mt = 0; mt < 4; mt++) {
                acc[mt][0] = __builtin_amdgcn_mfma_f32_16x16x32_bf16(ah[mt][kt], bh0, acc[mt][0], 0, 0, 0);
                acc[mt][1] = __builtin_amdgcn_mfma_f32_16x16x32_bf16(ah[mt][kt], bh1, acc[mt][1], 0, 0, 0);
                acc[mt][0] = __builtin_amdgcn_mfma_f32_16x16x32_bf16(al[mt][kt], bh0, acc[mt][0], 0, 0, 0);
                acc[mt][1] = __builtin_amdgcn_mfma_f32_16x16x32_bf16(al[mt][kt], bh1, acc[mt][1], 0, 0, 0);
                acc[mt][0] = __builtin_amdgcn_mfma_f32_16x16x32_bf16(ah[mt][kt], bl0, acc[mt][0], 0, 0, 0);
                acc[mt][1] = __builtin_amdgcn_mfma_f32_16x16x32_bf16(ah[mt][kt], bl1, acc[mt][1], 0, 0, 0);
            }
        }

        const int   kb  = c * 64 + wn * 32 + col;
        const float c20 = c2q[kb];
        const float c21 = c2q[kb + 16];
        #pragma unroll
        for (int mt = 0; mt < 4; mt++) {
            #pragma unroll
            for (int r = 0; r < 4; r++) {
                const int sl = mt * 4 + r;
                {
                    float s = fmaf(-2.0f, acc[mt][0][r], c20);
                    bool  b = s < s1[sl];
                    s2[sl] = fminf(s2[sl], fmaxf(s1[sl], s));
                    s1[sl] = fminf(s1[sl], s);
                    k1[sl] = b ? kb : k1[sl];
                }
                {
                    float s = fmaf(-2.0f, acc[mt][1][r], c21);
                    bool  b = s < s1[sl];
                    s2[sl] = fminf(s2[sl], fmaxf(s1[sl], s));
                    s1[sl] = fminf(s1[sl], s);
                    k1[sl] = b ? (kb + 16) : k1[sl];
                }
            }
        }
    }

    // cross-lane top-2 merge per row via LDS (stride 33 to avoid bank conflicts)
    __syncthreads();
    float* rs1 = (float*)smem;                 // [128][33]
    int*   rk1 = (int*)(smem + 16896);
    float* rs2 = (float*)(smem + 33792);
    #pragma unroll
    for (int mt = 0; mt < 4; mt++) {
        #pragma unroll
        for (int r = 0; r < 4; r++) {
            int sl = mt * 4 + r;
            int row_l = wm * 64 + mt * 16 + quad * 4 + r;
            int e = wn * 16 + col;
            rs1[row_l * 33 + e] = s1[sl];
            rk1[row_l * 33 + e] = k1[sl];
            rs2[row_l * 33 + e] = s2[sl];
        }
    }
    __syncthreads();
    if (t < 128) {
        float bs = FLT_MAX, bs2 = FLT_MAX;
        int   bk = 0x7fffffff;
        for (int e = 0; e < 32; e++) {
            float s   = rs1[t * 33 + e];
            int   k   = rk1[t * 33 + e];
            float s2e = rs2[t * 33 + e];
            bs2 = fminf(fminf(bs2, s2e), fmaxf(bs, s));
            if (s < bs || (s == bs && k < bk)) { bs = s; bk = k; }
        }
        int rg = row0 + t;
        idxi[rg * Q_ + q] = bk;
        idxf[rg * Q_ + q] = (float)bk;
        if (bs2 - bs < TAU) {
            int p = atomicAdd(counter, 1);
            list[p] = rg * Q_ + q;
        }
    }
}

// ---------------- exact fp32 re-score of flagged (row,q) pairs ----------------
__global__ void k_rescue(const float* __restrict__ xn, const float* __restrict__ cb,
                         const float* __restrict__ c2, const int* __restrict__ list,
                         const int* __restrict__ counter, int* __restrict__ idxi,
                         float* __restrict__ idxf) {
    __shared__ float xq[128];
    __shared__ float bs_sh[256];
    __shared__ int   bk_sh[256];
    const int n = *counter;
    const int t = threadIdx.x;
    for (int it = blockIdx.x; it < n; it += gridDim.x) {
        __syncthreads();
        int item = list[it];
        int rg = item >> 3, q = item & 7;
        if (t < 128) xq[t] = xn[(size_t)rg * D_ + q * dd_ + t];
        __syncthreads();
        float bs = FLT_MAX; int bk = 0x7fffffff;
        for (int i = 0; i < 16; i++) {
            int k = i * 256 + t;
            const float* cp = cb + ((size_t)q * K_ + k) * dd_;
            float dot = 0.0f;
            #pragma unroll 8
            for (int d = 0; d < dd_; d += 4) {
                f32x4 cv = *(const f32x4*)(cp + d);
                dot = fmaf(cv.x, xq[d],     dot);
                dot = fmaf(cv.y, xq[d + 1], dot);
                dot = fmaf(cv.z, xq[d + 2], dot);
                dot = fmaf(cv.w, xq[d + 3], dot);
            }
            float s = c2[q * K_ + k] - 2.0f * dot;
            if (s < bs || (s == bs && k < bk)) { bs = s; bk = k; }
        }
        bs_sh[t] = bs; bk_sh[t] = bk;
        __syncthreads();
        if (t == 0) {
            float B = FLT_MAX; int K2 = 0x7fffffff;
            for (int e = 0; e < 256; e++) {
                if (bs_sh[e] < B || (bs_sh[e] == B && bk_sh[e] < K2)) { B = bs_sh[e]; K2 = bk_sh[e]; }
            }
            idxi[item] = K2;
            idxf[item] = (float)K2;
        }
    }
}

// ---------------- gather + output rmsnorm ----------------
__global__ void k_out(const float* __restrict__ cb, const int* __restrict__ idx_i,
                      const float* __restrict__ w, float* __restrict__ out) {
    int row = blockIdx.x;
    int t   = threadIdx.x;
    __shared__ int   sidx[Q_];
    __shared__ float acc[4];
    if (t < Q_) sidx[t] = idx_i[row * Q_ + t];
    __syncthreads();
    int col = t * 4;
    int q   = col >> 7;
    int dc  = col & 127;
    const float4 v = *(const float4*)(cb + ((size_t)q * K_ + sidx[q]) * dd_ + dc);
    float ss = v.x * v.x + v.y * v.y + v.z * v.z + v.w * v.w;
    #pragma unroll
    for (int o = 32; o > 0; o >>= 1) ss += __shfl_xor(ss, o, 64);
    if ((t & 63) == 0) acc[t >> 6] = ss;
    __syncthreads();
    float tot = (acc[0] + acc[1]) + (acc[2] + acc[3]);
    float sc  = 1.0f / sqrtf(tot * (1.0f / D_) + 1e-5f);
    const float4 wv = *(const float4*)(w + col);
    float4 o;
    o.x = v.x * sc * wv.x; o.y = v.y * sc * wv.y;
    o.z = v.z * sc * wv.z; o.w = v.w * sc * wv.w;
    *(float4*)(out + (size_t)row * D_ + col) = o;
}

extern "C" void kernel_launch(void* const* d_in, const int* in_sizes, int n_in,
                              void* d_out, int out_size, void* d_ws, size_t ws_size,
                              hipStream_t stream) {
    const float* x     = (const float*)d_in[0];
    const float* cb    = (const float*)d_in[1];
    const float* w_in  = (const float*)d_in[2];
    const float* w_out = (const float*)d_in[3];

    float* out  = (float*)d_out;
    float* idxf = out + (size_t)ROWS * D_;

    // ws: panels 16MB | c2 128KB | list 256KB | counter | idxi 256KB  (~16.7MB)
    unsigned short* panels = (unsigned short*)d_ws;
    float* c2      = (float*)((char*)d_ws + (16u << 20));
    int*   list    = (int*)((char*)d_ws + (16u << 20) + (128u << 10));
    int*   counter = list + 65536;
    int*   idxi    = counter + 64;

    k_prep  <<<dim3(NCHUNK, Q_),     256, 0, stream>>>(cb, panels, c2, counter);
    k_rms_in<<<dim3(ROWS),           256, 0, stream>>>(x, w_in, out);
    k_dist  <<<dim3(ROWS / 128, Q_), 256, 0, stream>>>(out, panels, c2, idxi, idxf, list, counter);
    k_rescue<<<dim3(256),            256, 0, stream>>>(out, cb, c2, list, counter, idxi, idxf);
    k_out   <<<dim3(ROWS),           256, 0, stream>>>(cb, idxi, w_out, out);
}